// Round 3
// baseline (3270.167 us; speedup 1.0000x reference)
//
#include <hip/hip_runtime.h>
#include <cstdint>
#include <cstddef>

typedef unsigned short u16;
typedef unsigned int u32;
typedef unsigned long long u64;
typedef __attribute__((ext_vector_type(8))) short short8;   // 8 x bf16
typedef __attribute__((ext_vector_type(4))) float f32x4;

#define MFMA16(a, b, c) __builtin_amdgcn_mfma_f32_16x16x32_bf16((a), (b), (c), 0, 0, 0)
#define SCOPE_AGENT __HIP_MEMORY_SCOPE_AGENT

// B=64, T=512, D=512, H=1024.
// hi/lo bf16 split everywhere: fp32-grade via 3 MFMA products (R1/R2 absmax 0.0039).

static __device__ __forceinline__ u16 f2bf_rne(float f) {
  uint32_t u = __float_as_uint(f);
  u += 0x7FFFu + ((u >> 16) & 1u);
  return (u16)(u >> 16);
}
static __device__ __forceinline__ float bf2f(u16 h) {
  return __uint_as_float((uint32_t)h << 16);
}

// ---------------- prep ----------------
__global__ void split_arr(const float* __restrict__ src, u16* __restrict__ hi,
                          u16* __restrict__ lo, int n) {
  int i = blockIdx.x * blockDim.x + threadIdx.x;
  if (i >= n) return;
  float f = src[i];
  u16 h = f2bf_rne(f);
  hi[i] = h;
  lo[i] = f2bf_rne(f - bf2f(h));
}

__global__ void bias_init(const float* __restrict__ a, const float* __restrict__ b,
                          float* __restrict__ o, u32* __restrict__ flags) {
  int i = blockIdx.x * blockDim.x + threadIdx.x;
  if (i < 1024) o[i] = a[i] + b[i];
  if (i < 512)  // 4 bg x 128 per-(wg,wave) flags — zero before rnn (ws is 0xAA-poisoned)
    __hip_atomic_store(flags + i, 0u, __ATOMIC_RELAXED, SCOPE_AGENT);
}

// ---------------- phase 1: xin = x @ W_in^T + bsum -> d_out (unchanged) ----------------
__global__ __launch_bounds__(256) void xin_gemm(
    const float* __restrict__ x, const u16* __restrict__ Bh, const u16* __restrict__ Bl,
    const float* __restrict__ bsum, float* __restrict__ out) {
  __shared__ u16 Ahi[64 * 40], Alo[64 * 40], Bhi[64 * 40], Blo[64 * 40];
  const int mb = blockIdx.y * 64, nb = blockIdx.x * 64;
  const int tid = threadIdx.x, wave = tid >> 6, lane = tid & 63;
  const int mn = lane & 15, q = lane >> 4;
  const int srow = tid >> 2, scg = tid & 3;

  f32x4 acc[4] = {};
  for (int kb = 0; kb < 512; kb += 32) {
    const float* ap = x + (size_t)(mb + srow) * 512 + kb + scg * 8;
    float4 a0 = *(const float4*)ap;
    float4 a1 = *(const float4*)(ap + 4);
    float av[8] = {a0.x, a0.y, a0.z, a0.w, a1.x, a1.y, a1.z, a1.w};
    short8 vh, vl;
#pragma unroll
    for (int j = 0; j < 8; ++j) {
      u16 h = f2bf_rne(av[j]);
      vh[j] = (short)h;
      vl[j] = (short)f2bf_rne(av[j] - bf2f(h));
    }
    short8 wh = *(const short8*)(Bh + (size_t)(nb + srow) * 512 + kb + scg * 8);
    short8 wl = *(const short8*)(Bl + (size_t)(nb + srow) * 512 + kb + scg * 8);

    __syncthreads();
    *(short8*)&Ahi[srow * 40 + scg * 8] = vh;
    *(short8*)&Alo[srow * 40 + scg * 8] = vl;
    *(short8*)&Bhi[srow * 40 + scg * 8] = wh;
    *(short8*)&Blo[srow * 40 + scg * 8] = wl;
    __syncthreads();

    short8 ah = *(const short8*)&Ahi[(wave * 16 + mn) * 40 + q * 8];
    short8 al = *(const short8*)&Alo[(wave * 16 + mn) * 40 + q * 8];
#pragma unroll
    for (int nt = 0; nt < 4; ++nt) {
      short8 bh8 = *(const short8*)&Bhi[(nt * 16 + mn) * 40 + q * 8];
      short8 bl8 = *(const short8*)&Blo[(nt * 16 + mn) * 40 + q * 8];
      acc[nt] = MFMA16(ah, bh8, acc[nt]);
      acc[nt] = MFMA16(al, bh8, acc[nt]);
      acc[nt] = MFMA16(ah, bl8, acc[nt]);
    }
  }
#pragma unroll
  for (int nt = 0; nt < 4; ++nt)
#pragma unroll
    for (int r = 0; r < 4; ++r) {
      int row = mb + wave * 16 + q * 4 + r;
      int col = nb + nt * 16 + mn;
      out[(size_t)row * 1024 + col] = acc[nt][r] + bsum[col];
    }
}

// ---------------- phase 2: recurrence ----------------
// grid (32, 4): cg -> 32-col tile (W rows c0..c0+31 persistent in LDS, hi+lo),
// bg -> 16-batch group (fully independent). Distributed per-(wg,wave) monotone flags:
// producer wave drains ONLY its 8B h store, stores flag=t+2 (no RMW, no extra barrier).
// Consumer wave w polls exactly the 32 flags of its 8 K-slice producer wgs (one 128B
// line) -> partial wakeup. One __syncthreads per step (red[] double-buffered).
__global__ __launch_bounds__(256) void rnn_steps(
    const u16* __restrict__ Wh, const u16* __restrict__ Wl, u32* hbuf, u32* flags,
    float* __restrict__ io) {
  extern __shared__ __align__(16) char smem[];
  u16* Whi = (u16*)smem;                        // [32][1032]  66048 B
  u16* Wlo = (u16*)(smem + 66048);              // [32][1032]  66048 B
  float* red = (float*)(smem + 132096);         // [2][4][16][33] = 2 x 8448 B

  const int tid = threadIdx.x, wave = tid >> 6, lane = tid & 63;
  const int mn = lane & 15, q = lane >> 4;
  const int cg = blockIdx.x, bg = blockIdx.y;
  const int c0 = cg * 32, b0 = bg * 16;
  u32* bgflags = flags + bg * 128;              // [wg][wave]
  const u32* pollfl = bgflags + wave * 32;      // flags of wgs [8*wave, 8*wave+8)

  // persistent W tile: 32 rows x 1024, hi+lo
  for (int it = tid; it < 32 * 128; it += 256) {
    int r = it >> 7, c = it & 127;
    *(short8*)&Whi[r * 1032 + c * 8] = *(const short8*)(Wh + (size_t)(c0 + r) * 1024 + c * 8);
    *(short8*)&Wlo[r * 1032 + c * 8] = *(const short8*)(Wl + (size_t)(c0 + r) * 1024 + c * 8);
  }

  // zero h0 slice (buffer 0): my (16 batches x 32 cols) = 256 u64
  {
    u64* hz = (u64*)(hbuf) + ((size_t)b0 * 1024 + c0) / 2;
    for (int i = tid; i < 256; i += 256) {
      int b = i >> 4, cpair = i & 15;
      __hip_atomic_store(hz + b * 512 + cpair, 0ull, __ATOMIC_RELAXED, SCOPE_AGENT);
    }
  }
  asm volatile("s_waitcnt vmcnt(0)" ::: "memory");
  __syncthreads();  // all 4 waves' zero-stores drained
  if (lane == 0) __hip_atomic_store(bgflags + cg * 4 + wave, 1u, __ATOMIC_RELAXED, SCOPE_AGENT);

  // output ownership: 16 batches x 32 cols, 2 cols/thread
  const int om = tid >> 4, on2 = (tid & 15) * 2;
  const size_t iobase = ((size_t)(b0 + om) * 512) * 1024 + c0 + on2;
  float2 xv = *(const float2*)(io + iobase);  // t=0

  for (int t = 0; t < 512; ++t) {
    // ---- wait for my K-slice producers to publish h(t) ----
    const u32 target = (u32)(t + 1);
    for (;;) {
      u32 v = __hip_atomic_load(pollfl + (lane & 31), __ATOMIC_RELAXED, SCOPE_AGENT);
      if (__ballot(v >= target) == ~0ull) break;
      __builtin_amdgcn_s_sleep(2);
    }

    const u32* cur = hbuf + ((size_t)(t & 1) << 16);
    u32* nxt = hbuf + ((size_t)((t + 1) & 1) << 16);
    float* redt = red + (t & 1) * 2112;

    f32x4 acc[2] = {};
    const int kbase = wave * 256;
#pragma unroll
    for (int kt = 0; kt < 8; ++kt) {
      const int k = kbase + kt * 32 + q * 8;
      short8 ah, al;
      {
        const u64* p = (const u64*)(cur + (size_t)(b0 + mn) * 1024 + k);
#pragma unroll
        for (int i = 0; i < 4; ++i) {
          u64 d = __hip_atomic_load(p + i, __ATOMIC_RELAXED, SCOPE_AGENT);
          u32 w0 = (u32)d, w1 = (u32)(d >> 32);
          ah[2 * i]     = (short)(w0 >> 16);
          al[2 * i]     = (short)(w0 & 0xffffu);
          ah[2 * i + 1] = (short)(w1 >> 16);
          al[2 * i + 1] = (short)(w1 & 0xffffu);
        }
      }
#pragma unroll
      for (int nt = 0; nt < 2; ++nt) {
        short8 bh = *(const short8*)&Whi[(nt * 16 + mn) * 1032 + k];
        short8 bl = *(const short8*)&Wlo[(nt * 16 + mn) * 1032 + k];
        acc[nt] = MFMA16(ah, bh, acc[nt]);
        acc[nt] = MFMA16(al, bh, acc[nt]);
        acc[nt] = MFMA16(ah, bl, acc[nt]);
      }
    }
    // cross-wave K-reduction partials (double-buffered -> one barrier per step)
#pragma unroll
    for (int nt = 0; nt < 2; ++nt)
#pragma unroll
      for (int r = 0; r < 4; ++r)
        redt[wave * 528 + (q * 4 + r) * 33 + nt * 16 + mn] = acc[nt][r];
    __syncthreads();

    float s0 = 0.f, s1 = 0.f;
#pragma unroll
    for (int w = 0; w < 4; ++w) {
      s0 += redt[w * 528 + om * 33 + on2];
      s1 += redt[w * 528 + om * 33 + on2 + 1];
    }
    float o0 = tanhf(s0 + xv.x);
    float o1 = tanhf(s1 + xv.y);

    if (t < 511) {
      // publish h(t+1): 8B store, drain ONLY it, then flag. io/prefetch after (off path).
      u16 h0 = f2bf_rne(o0), h1 = f2bf_rne(o1);
      u32 p0 = ((u32)h0 << 16) | f2bf_rne(o0 - bf2f(h0));
      u32 p1 = ((u32)h1 << 16) | f2bf_rne(o1 - bf2f(h1));
      u64* hp = (u64*)(nxt + (size_t)(b0 + om) * 1024 + c0 + on2);
      __hip_atomic_store(hp, ((u64)p1 << 32) | p0, __ATOMIC_RELAXED, SCOPE_AGENT);
      asm volatile("s_waitcnt vmcnt(0)" ::: "memory");
      if (lane == 0)
        __hip_atomic_store(bgflags + cg * 4 + wave, (u32)(t + 2), __ATOMIC_RELAXED, SCOPE_AGENT);
    }
    *(float2*)(io + iobase + (size_t)t * 1024) = make_float2(o0, o1);  // h_t -> output
    if (t < 511) xv = *(const float2*)(io + iobase + (size_t)(t + 1) * 1024);  // prefetch
  }
}

// ---------------- host ----------------
extern "C" void kernel_launch(void* const* d_in, const int* in_sizes, int n_in, void* d_out,
                              int out_size, void* d_ws, size_t ws_size, hipStream_t stream) {
  (void)in_sizes; (void)n_in; (void)out_size; (void)ws_size;
  const float* x    = (const float*)d_in[0];
  const float* W_in = (const float*)d_in[1];
  const float* b_in = (const float*)d_in[2];
  const float* W_hh = (const float*)d_in[3];
  const float* bias = (const float*)d_in[4];
  float* out = (float*)d_out;
  char* ws = (char*)d_ws;

  u16* win_hi = (u16*)(ws);
  u16* win_lo = (u16*)(ws + (1u << 20));
  u16* whh_hi = (u16*)(ws + (2u << 20));
  u16* whh_lo = (u16*)(ws + (4u << 20));
  float* bsum = (float*)(ws + (6u << 20));
  u32* hbuf   = (u32*)(ws + (6u << 20) + 65536);           // 2 x 64*1024 u32 = 512 KB
  u32* flags  = (u32*)(ws + (6u << 20) + 65536 + 524288);  // 4 bg x 128 u32

  split_arr<<<dim3(524288 / 256), dim3(256), 0, stream>>>(W_in, win_hi, win_lo, 524288);
  split_arr<<<dim3(1048576 / 256), dim3(256), 0, stream>>>(W_hh, whh_hi, whh_lo, 1048576);
  bias_init<<<dim3(4), dim3(256), 0, stream>>>(b_in, bias, bsum, flags);

  xin_gemm<<<dim3(16, 512), dim3(256), 0, stream>>>(x, win_hi, win_lo, bsum, out);

  static const unsigned kSmem = 148992;  // 2*66048 + 2*8448
  hipFuncSetAttribute((const void*)rnn_steps, hipFuncAttributeMaxDynamicSharedMemorySize,
                      (int)kSmem);
  void* args[5];
  args[0] = (void*)&whh_hi;
  args[1] = (void*)&whh_lo;
  args[2] = (void*)&hbuf;
  args[3] = (void*)&flags;
  args[4] = (void*)&out;
  hipLaunchCooperativeKernel((const void*)rnn_steps, dim3(32, 4), dim3(256, 1, 1), args, kSmem,
                             stream);
}